// Round 12
// baseline (30.951 us; speedup 1.0000x reference)
//
#include <hip/hip_runtime.h>
#include <float.h>

#define H_IN 224
#define W_IN 224
#define H_T  240
#define W_T  240
#define S1   17
#define S2   17
#define NS   (S1*S2)          // 289
#define NB   8
#define NPIX (H_IN*W_IN)      // 50176
#define TPIX (H_T*W_T)        // 57600
#define RG   8                // stripe-blocks per sample (part layout, as R8)
#define IG   5                // i-groups: {0-3,4-7,8-11,12-15,16}
#define ROWS_PER_BLOCK (H_IN/RG)          // 28
#define ROWS_PER_WAVE  (ROWS_PER_BLOCK/4) // 7
#define PB   (NPIX/256)       // 196 copy-blocks per sample

// ws float layout (identical to R8):
//   part : [B][S1][RG][S2]  -> 18496 floats @ 0
//   fpart: [B][RG]          -> 64 floats @ 18496
#define WS_PART  0
#define WS_FPART 18496

// ---------------- kernel 1: i-blocked corr + f(l) on tail blocks ----------------
// block = (ig, b, blk): computes shifts i = ig*4 .. ig*4+3 (tail ig=4: i=16 only)
// for row stripe blk. Wave holds 7 L-rows in regs; each T-row loaded once serves
// up to 4 i's: 5 loads -> up to 272 FMAs (4x arithmetic intensity vs R8).
__global__ __launch_bounds__(256) void corr_f_kernel(const float* __restrict__ logits,
                                                     const float* __restrict__ targ,
                                                     float* __restrict__ ws) {
    int bid  = blockIdx.x;              // (ig*NB + b)*RG + blk  (heavy ig first)
    int blk  = bid % RG;
    int b    = (bid / RG) % NB;
    int ig   = bid / (RG * NB);
    int tid  = threadIdx.x;
    int lane = tid & 63;
    int w    = tid >> 6;
    bool active = lane < (W_IN / 4);    // 56 active lanes

    const int y0 = blk * ROWS_PER_BLOCK + w * ROWS_PER_WAVE;
    const int i0 = ig * 4;
    const bool tail = (ig == IG - 1);
    const bool do_f = tail;             // f(l) on the light blocks

    float acc0[S2]={0.f,0.f,0.f,0.f,0.f,0.f,0.f,0.f,0.f,0.f,0.f,0.f,0.f,0.f,0.f,0.f,0.f};
    float acc1[S2]={0.f,0.f,0.f,0.f,0.f,0.f,0.f,0.f,0.f,0.f,0.f,0.f,0.f,0.f,0.f,0.f,0.f};
    float acc2[S2]={0.f,0.f,0.f,0.f,0.f,0.f,0.f,0.f,0.f,0.f,0.f,0.f,0.f,0.f,0.f,0.f,0.f};
    float acc3[S2]={0.f,0.f,0.f,0.f,0.f,0.f,0.f,0.f,0.f,0.f,0.f,0.f,0.f,0.f,0.f,0.f,0.f};
    float fs = 0.f;

    const float* Lb = logits + b * NPIX;
    const float* Tb = targ   + b * TPIX;

    if (active) {
        const float4 Lr0 = *(const float4*)(Lb + (y0+0)*W_IN + lane*4);
        const float4 Lr1 = *(const float4*)(Lb + (y0+1)*W_IN + lane*4);
        const float4 Lr2 = *(const float4*)(Lb + (y0+2)*W_IN + lane*4);
        const float4 Lr3 = *(const float4*)(Lb + (y0+3)*W_IN + lane*4);
        const float4 Lr4 = *(const float4*)(Lb + (y0+4)*W_IN + lane*4);
        const float4 Lr5 = *(const float4*)(Lb + (y0+5)*W_IN + lane*4);
        const float4 Lr6 = *(const float4*)(Lb + (y0+6)*W_IN + lane*4);

        if (do_f) {
#define FSUM(LV) { fs += fmaxf(LV.x,0.f) + __logf(1.f+__expf(-fabsf(LV.x))); \
                   fs += fmaxf(LV.y,0.f) + __logf(1.f+__expf(-fabsf(LV.y))); \
                   fs += fmaxf(LV.z,0.f) + __logf(1.f+__expf(-fabsf(LV.z))); \
                   fs += fmaxf(LV.w,0.f) + __logf(1.f+__expf(-fabsf(LV.w))); }
            FSUM(Lr0) FSUM(Lr1) FSUM(Lr2) FSUM(Lr3) FSUM(Lr4) FSUM(Lr5) FSUM(Lr6)
#undef FSUM
        }

        float T[20];
#define LOADT(TR) { const float* Tr_ = Tb + (TR)*W_T + lane*4;                          \
        const float4 ta_=*(const float4*)(Tr_);      const float4 tb_=*(const float4*)(Tr_+4); \
        const float4 tc_=*(const float4*)(Tr_+8);    const float4 td_=*(const float4*)(Tr_+12);\
        const float4 te_=*(const float4*)(Tr_+16);                                      \
        T[0]=ta_.x; T[1]=ta_.y; T[2]=ta_.z; T[3]=ta_.w;                                 \
        T[4]=tb_.x; T[5]=tb_.y; T[6]=tb_.z; T[7]=tb_.w;                                 \
        T[8]=tc_.x; T[9]=tc_.y; T[10]=tc_.z; T[11]=tc_.w;                               \
        T[12]=td_.x; T[13]=td_.y; T[14]=td_.z; T[15]=td_.w;                             \
        T[16]=te_.x; T[17]=te_.y; T[18]=te_.z; T[19]=te_.w; }
#define FMAJ(AG, LV, J) { float s_=AG[J]; s_=fmaf(LV.x,T[J],s_); s_=fmaf(LV.y,T[(J)+1],s_); \
        s_=fmaf(LV.z,T[(J)+2],s_); s_=fmaf(LV.w,T[(J)+3],s_); AG[J]=s_; }
#define ROW17(AG, LV) FMAJ(AG,LV,0)  FMAJ(AG,LV,1)  FMAJ(AG,LV,2)  FMAJ(AG,LV,3)  \
                      FMAJ(AG,LV,4)  FMAJ(AG,LV,5)  FMAJ(AG,LV,6)  FMAJ(AG,LV,7)  \
                      FMAJ(AG,LV,8)  FMAJ(AG,LV,9)  FMAJ(AG,LV,10) FMAJ(AG,LV,11) \
                      FMAJ(AG,LV,12) FMAJ(AG,LV,13) FMAJ(AG,LV,14) FMAJ(AG,LV,15) FMAJ(AG,LV,16)

        if (!tail) {
            // t_rel = y_rel + g; compile-time (g, y_rel) pairs per step
            LOADT(y0+i0+0) ROW17(acc0,Lr0)
            LOADT(y0+i0+1) ROW17(acc0,Lr1) ROW17(acc1,Lr0)
            LOADT(y0+i0+2) ROW17(acc0,Lr2) ROW17(acc1,Lr1) ROW17(acc2,Lr0)
            LOADT(y0+i0+3) ROW17(acc0,Lr3) ROW17(acc1,Lr2) ROW17(acc2,Lr1) ROW17(acc3,Lr0)
            LOADT(y0+i0+4) ROW17(acc0,Lr4) ROW17(acc1,Lr3) ROW17(acc2,Lr2) ROW17(acc3,Lr1)
            LOADT(y0+i0+5) ROW17(acc0,Lr5) ROW17(acc1,Lr4) ROW17(acc2,Lr3) ROW17(acc3,Lr2)
            LOADT(y0+i0+6) ROW17(acc0,Lr6) ROW17(acc1,Lr5) ROW17(acc2,Lr4) ROW17(acc3,Lr3)
            LOADT(y0+i0+7)                 ROW17(acc1,Lr6) ROW17(acc2,Lr5) ROW17(acc3,Lr4)
            LOADT(y0+i0+8)                                 ROW17(acc2,Lr6) ROW17(acc3,Lr5)
            LOADT(y0+i0+9)                                                 ROW17(acc3,Lr6)
        } else {
            // single shift i=16 into acc0
            LOADT(y0+16+0) ROW17(acc0,Lr0)
            LOADT(y0+16+1) ROW17(acc0,Lr1)
            LOADT(y0+16+2) ROW17(acc0,Lr2)
            LOADT(y0+16+3) ROW17(acc0,Lr3)
            LOADT(y0+16+4) ROW17(acc0,Lr4)
            LOADT(y0+16+5) ROW17(acc0,Lr5)
            LOADT(y0+16+6) ROW17(acc0,Lr6)
        }
#undef ROW17
#undef FMAJ
#undef LOADT
    }

    __shared__ float red[4][4][S2];     // [wave][g][j]
    __shared__ float redf[4];

#define REDE(AG, G_, J) { float v_ = AG[J];     \
        v_ += __shfl_xor(v_, 32, 64);           \
        v_ += __shfl_xor(v_, 16, 64);           \
        v_ += __shfl_xor(v_,  8, 64);           \
        v_ += __shfl_xor(v_,  4, 64);           \
        v_ += __shfl_xor(v_,  2, 64);           \
        v_ += __shfl_xor(v_,  1, 64);           \
        if (lane == 0) red[w][G_][J] = v_; }
#define RED17(AG, G_) REDE(AG,G_,0)  REDE(AG,G_,1)  REDE(AG,G_,2)  REDE(AG,G_,3)  \
                      REDE(AG,G_,4)  REDE(AG,G_,5)  REDE(AG,G_,6)  REDE(AG,G_,7)  \
                      REDE(AG,G_,8)  REDE(AG,G_,9)  REDE(AG,G_,10) REDE(AG,G_,11) \
                      REDE(AG,G_,12) REDE(AG,G_,13) REDE(AG,G_,14) REDE(AG,G_,15) REDE(AG,G_,16)
    RED17(acc0, 0)
    if (!tail) { RED17(acc1, 1) RED17(acc2, 2) RED17(acc3, 3) }
#undef RED17
#undef REDE

    if (do_f) {
        fs += __shfl_xor(fs, 32, 64);
        fs += __shfl_xor(fs, 16, 64);
        fs += __shfl_xor(fs,  8, 64);
        fs += __shfl_xor(fs,  4, 64);
        fs += __shfl_xor(fs,  2, 64);
        fs += __shfl_xor(fs,  1, 64);
        if (lane == 0) redf[w] = fs;
    }
    __syncthreads();
    if (tid < 4 * S2) {
        int g = tid / S2, j = tid % S2;
        if (!tail || g == 0) {
            float v = red[0][g][j] + red[1][g][j] + red[2][g][j] + red[3][g][j];
            ws[WS_PART + ((b * S1 + (i0 + g)) * RG + blk) * S2 + j] = v;
        }
    }
    if (do_f && tid == 0)
        ws[WS_FPART + b * RG + blk] = redf[0] + redf[1] + redf[2] + redf[3];
}

// ---------------- kernel 2: argmax + copy + loss (identical to R8) ----------------
__device__ __forceinline__ float part_sum(const float* __restrict__ pp) {
    float v = 0.f;
#pragma unroll
    for (int k = 0; k < RG; ++k) v += pp[k * S2];
    return v;
}

__device__ __forceinline__ void argmax_for(const float* __restrict__ part, int bb,
                                           int tid, int lane, int w,
                                           float* s_v, int* s_i,
                                           float& o_v, int& o_i) {
    float bv = -FLT_MAX;
    int   bs = NS;
    for (int s = tid; s < NS; s += 256) {
        const float* pp = part + ((bb * S1 + s / S2) * RG) * S2 + (s % S2);
        float v = part_sum(pp);
        if (v > bv) { bv = v; bs = s; } // s ascending -> earliest tie kept
    }
#pragma unroll
    for (int off = 32; off > 0; off >>= 1) {
        float ov = __shfl_down(bv, off, 64);
        int   oi = __shfl_down(bs, off, 64);
        if (ov > bv || (ov == bv && oi < bs)) { bv = ov; bs = oi; }
    }
    if (lane == 0) { s_v[w] = bv; s_i[w] = bs; }
    __syncthreads();
    if (tid == 0) {
        float fv = s_v[0]; int fi = s_i[0];
#pragma unroll
        for (int k = 1; k < 4; ++k) {
            if (s_v[k] > fv || (s_v[k] == fv && s_i[k] < fi)) { fv = s_v[k]; fi = s_i[k]; }
        }
        s_v[4] = fv; s_i[4] = fi;
    }
    __syncthreads();
    o_v = s_v[4];
    o_i = s_i[4];
}

__device__ __forceinline__ void argmax_all8(const float* __restrict__ part,
                                            int lane, int w,
                                            float* s_v8, int* s_i8) {
#pragma unroll
    for (int pass = 0; pass < 2; ++pass) {
        int bb = w + pass * 4;
        float bv2 = -FLT_MAX;
        int   bs2 = NS;
        for (int s = lane; s < NS; s += 64) {
            const float* pp = part + ((bb * S1 + s / S2) * RG) * S2 + (s % S2);
            float v = part_sum(pp);
            if (v > bv2) { bv2 = v; bs2 = s; }
        }
#pragma unroll
        for (int off = 32; off > 0; off >>= 1) {
            float ov = __shfl_down(bv2, off, 64);
            int   oi = __shfl_down(bs2, off, 64);
            if (ov > bv2 || (ov == bv2 && oi < bs2)) { bv2 = ov; bs2 = oi; }
        }
        if (lane == 0) { s_v8[bb] = bv2; s_i8[bb] = bs2; }
    }
    __syncthreads();
}

__global__ __launch_bounds__(256) void finish_kernel(const float* __restrict__ targ,
                                                     const float* __restrict__ ws,
                                                     float* __restrict__ out) {
    int blk = blockIdx.x;               // b*PB + p
    int p   = blk % PB;
    int b   = blk / PB;
    int tid = threadIdx.x;
    int lane = tid & 63;
    int w    = tid >> 6;

    const float* part  = ws + WS_PART;
    const float* fpart = ws + WS_FPART;

    __shared__ float s_v[5];
    __shared__ int   s_i[5];
    __shared__ float s_v8[NB];
    __shared__ int   s_i8[NB];

    int best;
    if (blk == 0) {
        argmax_all8(part, lane, w, s_v8, s_i8);
        if (tid == 0) {
            float total = 0.f;
#pragma unroll
            for (int bb = 0; bb < NB; ++bb) {
                float F = 0.f;
#pragma unroll
                for (int k = 0; k < RG; ++k) F += fpart[bb * RG + k];
                total += (F - s_v8[bb]) * (1.0f / (float)NPIX);
            }
            out[0] = total;
        }
        best = s_i8[0];
    } else {
        float bv;
        argmax_for(part, b, tid, lane, w, s_v, s_i, bv, best);
    }

    int pix = p * 256 + tid;            // < 50176 exactly
    int y = pix / W_IN;
    int x = pix - y * W_IN;
    int i = best / S2;
    int j = best - i * S2;
    out[1 + b * NPIX + pix] = targ[b * TPIX + (y + i) * W_T + (x + j)];
}

extern "C" void kernel_launch(void* const* d_in, const int* in_sizes, int n_in,
                              void* d_out, int out_size, void* d_ws, size_t ws_size,
                              hipStream_t stream) {
    const float* logits = (const float*)d_in[0];   // [8,1,224,224]
    const float* targ   = (const float*)d_in[1];   // [8,1,240,240]
    float* out = (float*)d_out;                    // [1 + 8*224*224]
    float* ws  = (float*)d_ws;

    corr_f_kernel<<<IG * NB * RG, 256, 0, stream>>>(logits, targ, ws);
    finish_kernel<<<NB * PB, 256, 0, stream>>>(targ, ws, out);
}